// Round 1
// 223.854 us; speedup vs baseline: 1.0022x; 1.0022x over previous
//
#include <hip/hip_runtime.h>

// QLayerNorm (fp32 in / fp32 out): LayerNorm over D=1024 with the reference's
// 4-step fixed-point "sqrt": a = var + 5e-5; l1=(a/a+a)/2; l_{k+1}=(l_k/a + a)/2
// (divisor is ALWAYS a); out = (x-mean)/std * w + b.
//
// R4 (from R3's 224.3 us):
//  - a/a == 1.0f exactly (IEEE, a = var+eps > 0 normal) -> first step is (1+a)/2.
//  - Remaining /a and 1/std via v_rcp_f32 + 1 Newton step (rel err ~2^-44 vs
//    0.0156 abs tolerance). Kills the ~100-op serial v_div_* expansion chain.
//  - x nontemporal loads (HBM, long latency) issued BEFORE w/b (L1/L2-hot).
//  - Epilogue folded: out = fma(fma(x, is, -mean*is), w, b)  (2 ops/elem).

constexpr int D_DIM = 1024;
constexpr float EPS = 5e-5f;

typedef float vfloat4 __attribute__((ext_vector_type(4)));

__device__ __forceinline__ float fast_rcp(float a) {
    float r = __builtin_amdgcn_rcpf(a);          // v_rcp_f32, ~1 ulp
    return fmaf(r, fmaf(-a, r, 1.0f), r);        // 1 Newton step -> ~2^-44 rel
}

__global__ __launch_bounds__(256) void qln_kernel(
    const float* __restrict__ x,
    const float* __restrict__ w,
    const float* __restrict__ b,
    float* __restrict__ out,
    int nrows)
{
    const int gtid = blockIdx.x * blockDim.x + threadIdx.x;
    const int wid  = gtid >> 6;           // one wave per 2 rows
    const int lane = gtid & 63;
    const int r0 = wid * 2;
    const int r1 = r0 + 1;
    if (r0 >= nrows) return;
    const bool has2 = (r1 < nrows);       // wave-uniform

    const vfloat4* __restrict__ w4 = (const vfloat4*)w;
    const vfloat4* __restrict__ b4 = (const vfloat4*)b;
    const vfloat4* __restrict__ xr0 = (const vfloat4*)(x + (size_t)r0 * D_DIM);
    const vfloat4* __restrict__ xr1 = (const vfloat4*)(x + (size_t)r1 * D_DIM);

    // Streamed x first: HBM latency is the critical path; 16B/lane coalesced.
    vfloat4 v0[4], v1[4];
#pragma unroll
    for (int c = 0; c < 4; ++c)
        v0[c] = __builtin_nontemporal_load(&xr0[lane + 64 * c]);
    if (has2) {
#pragma unroll
        for (int c = 0; c < 4; ++c)
            v1[c] = __builtin_nontemporal_load(&xr1[lane + 64 * c]);
    } else {
#pragma unroll
        for (int c = 0; c < 4; ++c) v1[c] = (vfloat4)(0.f);
    }

    // w/b after x: these hit L1/L2 (4 KiB each, every block re-reads them);
    // their latency hides under the x-load wait + butterfly.
    vfloat4 wv[4], bv[4];
#pragma unroll
    for (int c = 0; c < 4; ++c) {
        wv[c] = w4[lane + 64 * c];
        bv[c] = b4[lane + 64 * c];
    }

    float sum0 = 0.f, sq0 = 0.f, sum1 = 0.f, sq1 = 0.f;
#pragma unroll
    for (int c = 0; c < 4; ++c) {
        sum0 += (v0[c].x + v0[c].y) + (v0[c].z + v0[c].w);
        sq0 = fmaf(v0[c].x, v0[c].x, sq0);
        sq0 = fmaf(v0[c].y, v0[c].y, sq0);
        sq0 = fmaf(v0[c].z, v0[c].z, sq0);
        sq0 = fmaf(v0[c].w, v0[c].w, sq0);
        sum1 += (v1[c].x + v1[c].y) + (v1[c].z + v1[c].w);
        sq1 = fmaf(v1[c].x, v1[c].x, sq1);
        sq1 = fmaf(v1[c].y, v1[c].y, sq1);
        sq1 = fmaf(v1[c].z, v1[c].z, sq1);
        sq1 = fmaf(v1[c].w, v1[c].w, sq1);
    }

    // 64-lane butterfly; two rows' chains interleave (independent).
#pragma unroll
    for (int m = 32; m >= 1; m >>= 1) {
        sum0 += __shfl_xor(sum0, m, 64);
        sq0  += __shfl_xor(sq0,  m, 64);
        sum1 += __shfl_xor(sum1, m, 64);
        sq1  += __shfl_xor(sq1,  m, 64);
    }

    const float invD = 1.0f / (float)D_DIM;
    const float mean0 = sum0 * invD;
    const float mean1 = sum1 * invD;
    const float var0 = fmaf(-mean0, mean0, sq0 * invD);
    const float var1 = fmaf(-mean1, mean1, sq1 * invD);
    const float a0 = var0 + EPS;
    const float a1 = var1 + EPS;

    // Fixed-point iteration, divisor always a.
    // Step 1: a/a == 1.0f exactly (a > 0, normal) -> (1+a)/2, bit-identical
    // to the reference. Steps 2-4: l/a via rcp (ra computes in parallel).
    const float ra0 = fast_rcp(a0);
    const float ra1 = fast_rcp(a1);
    float l0 = (1.0f + a0) * 0.5f;
    float l1 = (1.0f + a1) * 0.5f;
    l0 = fmaf(l0, ra0, a0) * 0.5f;
    l1 = fmaf(l1, ra1, a1) * 0.5f;
    l0 = fmaf(l0, ra0, a0) * 0.5f;
    l1 = fmaf(l1, ra1, a1) * 0.5f;
    const float std0 = fmaf(l0, ra0, a0) * 0.5f;
    const float std1 = fmaf(l1, ra1, a1) * 0.5f;
    const float is0 = fast_rcp(std0);
    const float is1 = fast_rcp(std1);
    const float mis0 = -mean0 * is0;     // out = (x*is - mean*is)*w + b
    const float mis1 = -mean1 * is1;

    vfloat4* __restrict__ o0 = (vfloat4*)(out + (size_t)r0 * D_DIM);
#pragma unroll
    for (int c = 0; c < 4; ++c) {
        vfloat4 ov;
        ov.x = fmaf(fmaf(v0[c].x, is0, mis0), wv[c].x, bv[c].x);
        ov.y = fmaf(fmaf(v0[c].y, is0, mis0), wv[c].y, bv[c].y);
        ov.z = fmaf(fmaf(v0[c].z, is0, mis0), wv[c].z, bv[c].z);
        ov.w = fmaf(fmaf(v0[c].w, is0, mis0), wv[c].w, bv[c].w);
        __builtin_nontemporal_store(ov, &o0[lane + 64 * c]);
    }
    if (has2) {
        vfloat4* __restrict__ o1 = (vfloat4*)(out + (size_t)r1 * D_DIM);
#pragma unroll
        for (int c = 0; c < 4; ++c) {
            vfloat4 ov;
            ov.x = fmaf(fmaf(v1[c].x, is1, mis1), wv[c].x, bv[c].x);
            ov.y = fmaf(fmaf(v1[c].y, is1, mis1), wv[c].y, bv[c].y);
            ov.z = fmaf(fmaf(v1[c].z, is1, mis1), wv[c].z, bv[c].z);
            ov.w = fmaf(fmaf(v1[c].w, is1, mis1), wv[c].w, bv[c].w);
            __builtin_nontemporal_store(ov, &o1[lane + 64 * c]);
        }
    }
}

extern "C" void kernel_launch(void* const* d_in, const int* in_sizes, int n_in,
                              void* d_out, int out_size, void* d_ws, size_t ws_size,
                              hipStream_t stream) {
    const float* x = (const float*)d_in[0];
    const float* w = (const float*)d_in[1];
    const float* b = (const float*)d_in[2];
    float* out = (float*)d_out;

    const int nrows = in_sizes[0] / D_DIM;            // 32768 rows
    const int nwaves = (nrows + 1) / 2;               // 2 rows per wave
    const int threads = 256;                           // 4 waves per block
    const int blocks = (nwaves * 64 + threads - 1) / threads;
    qln_kernel<<<blocks, threads, 0, stream>>>(x, w, b, out, nrows);
}